// Round 11
// baseline (276.857 us; speedup 1.0000x reference)
//
#include <hip/hip_runtime.h>

#define RES 128
#define RES_V 129
#define N_VOX 400000

constexpr int N_VERTS = RES_V * RES_V * RES_V;   // 2146689
constexpr int N_CELLS = RES * RES * RES;         // 2097152
constexpr long VOUT_WORDS = (long)N_VERTS * 10;  // 21466890
constexpr long OUTW_WORDS = (long)N_CELLS * 21;  // 44040192
constexpr int SCAN_BLOCKS = 512;                 // N_CELLS / 4096
constexpr int GATHER_BLOCKS = (N_VERTS + 255) / 256;  // 8386
constexpr float SDF_BIAS = -1.0f / 128.0f;
constexpr float DEFORM_SCALE = (float)((1.0 - 1e-8) / 256.0);
constexpr float INV_RES = 1.0f / 128.0f;
// perm layout: 48 uints (192B) per slot, 6 uints (24B) per corner chunk
// (20B useful + 4B pad) -> every chunk is 8B-aligned for uint2 loads.

// bf16 pack/unpack (round-to-nearest-even)
static __device__ __forceinline__ unsigned int f2bf(float x) {
    unsigned int u = __float_as_uint(x);
    unsigned int r = ((u >> 16) & 1u) + 0x7FFFu;
    return (u + r) >> 16;
}
static __device__ __forceinline__ float bf_lo(unsigned int w) {
    return __uint_as_float(w << 16);
}
static __device__ __forceinline__ float bf_hi(unsigned int w) {
    return __uint_as_float(w & 0xFFFF0000u);
}

// accumulate corner chunk c of perm row ii into sums[10]
static __device__ __forceinline__ void acc_row(const unsigned int* __restrict__ perm,
                                               long ii, int c, float* sums) {
    const unsigned int* b = perm + ii * 48 + c * 6;
    uint2 p01 = *(const uint2*)(b);
    uint2 p23 = *(const uint2*)(b + 2);
    unsigned int w4 = b[4];
    sums[0] += bf_lo(p01.x); sums[1] += bf_hi(p01.x);
    sums[2] += bf_lo(p01.y); sums[3] += bf_hi(p01.y);
    sums[4] += bf_lo(p23.x); sums[5] += bf_hi(p23.x);
    sums[6] += bf_lo(p23.y); sums[7] += bf_hi(p23.y);
    sums[8] += bf_lo(w4);    sums[9] += bf_hi(w4);
}

// --- K1: per-voxel cell histogram ---
__global__ void __launch_bounds__(256) count_kernel(const int* __restrict__ coords,
                                                    unsigned int* __restrict__ counts)
{
    int n = blockIdx.x * blockDim.x + threadIdx.x;
    if (n >= N_VOX) return;
    int cx = coords[n * 3 + 0];
    int cy = coords[n * 3 + 1];
    int cz = coords[n * 3 + 2];
    int cid = (cx * RES + cy) * RES + cz;
    atomicAdd(counts + cid, 1u);
}

// --- K2: block-local exclusive scan (4096 elems / block) -> packed(local) ---
__global__ void __launch_bounds__(256) scan1_kernel(const unsigned int* __restrict__ counts,
                                                    unsigned int* __restrict__ packed,
                                                    unsigned int* __restrict__ blocksums)
{
    __shared__ unsigned int part[256];
    int b = blockIdx.x, t = threadIdx.x;
    long base = (long)b * 4096 + (long)t * 16;
    unsigned int v[16], s = 0;
#pragma unroll
    for (int i = 0; i < 16; ++i) { v[i] = counts[base + i]; s += v[i]; }
    part[t] = s;
    __syncthreads();
    for (int off = 1; off < 256; off <<= 1) {
        unsigned int x = (t >= off) ? part[t - off] : 0u;
        __syncthreads();
        part[t] += x;
        __syncthreads();
    }
    unsigned int excl = (t == 0) ? 0u : part[t - 1];
    if (t == 255) blocksums[b] = part[255];
    unsigned int run = excl;
#pragma unroll
    for (int i = 0; i < 16; ++i) { packed[base + i] = run; run += v[i]; }
}

// --- K3: globalize + pack count into high byte; init cursors; sentinel ---
__global__ void __launch_bounds__(256) fixup2_kernel(unsigned int* __restrict__ packed,
                                                     unsigned int* __restrict__ cnt_cursor,
                                                     const unsigned int* __restrict__ blocksums)
{
    __shared__ unsigned int red[256];
    int t = threadIdx.x;
    int cell0 = blockIdx.x * 256;
    int R = cell0 >> 12;                 // how many 4096-regions precede us
    unsigned int part = 0;
    for (int j = t; j < R; j += 256) part += blocksums[j];
    red[t] = part;
    __syncthreads();
    for (int off = 128; off > 0; off >>= 1) {
        if (t < off) red[t] += red[t + off];
        __syncthreads();
    }
    unsigned int P = red[0];
    int cell = cell0 + t;
    unsigned int g = packed[cell] + P;
    unsigned int cnt = cnt_cursor[cell];
    packed[cell] = g | (min(cnt, 255u) << 24);
    cnt_cursor[cell] = g;
    if (cell == 0) packed[N_CELLS] = (unsigned int)N_VOX;
}

// --- K4: fill CSR list ---
__global__ void __launch_bounds__(256) fill_kernel(const int* __restrict__ coords,
                                                   unsigned int* __restrict__ cursors,
                                                   unsigned int* __restrict__ list)
{
    int n = blockIdx.x * blockDim.x + threadIdx.x;
    if (n >= N_VOX) return;
    int cx = coords[n * 3 + 0];
    int cy = coords[n * 3 + 1];
    int cz = coords[n * 3 + 2];
    int cid = (cx * RES + cy) * RES + cz;
    unsigned int slot = atomicAdd(cursors + cid, 1u);
    list[slot] = (unsigned int)n;
}

// --- K5: permute feats into cell-sorted, corner-SoA bf16 rows (padded) ---
__global__ void __launch_bounds__(256) permute_kernel(const float* __restrict__ feats,
                                                      const unsigned int* __restrict__ list,
                                                      unsigned int* __restrict__ perm)
{
    int g = blockIdx.x * blockDim.x + threadIdx.x;
    int slot = g >> 3;
    int c = g & 7;
    if (slot >= N_VOX) return;
    long src = (long)list[slot] * 101;
    float v[10];
    v[0] = feats[src + c];
#pragma unroll
    for (int k = 0; k < 3; ++k) v[1 + k] = feats[src + 8 + 3 * c + k];
#pragma unroll
    for (int k = 0; k < 6; ++k) v[4 + k] = feats[src + 53 + 6 * c + k];
    unsigned int* d = perm + (long)slot * 48 + c * 6;
    unsigned int w0 = f2bf(v[0]) | (f2bf(v[1]) << 16);
    unsigned int w1 = f2bf(v[2]) | (f2bf(v[3]) << 16);
    unsigned int w2 = f2bf(v[4]) | (f2bf(v[5]) << 16);
    unsigned int w3 = f2bf(v[6]) | (f2bf(v[7]) << 16);
    unsigned int w4 = f2bf(v[8]) | (f2bf(v[9]) << 16);
    *(uint2*)(d)     = make_uint2(w0, w1);
    *(uint2*)(d + 2) = make_uint2(w2, w3);
    d[4] = w4;
}

// --- K6: aggregate multi-voxel cells: row s := sum of rows s..e (f32 acc) ---
// After this, every occupied cell's contribution is exactly ONE row read.
__global__ void __launch_bounds__(256) aggregate_kernel(const unsigned int* __restrict__ packed,
                                                        unsigned int* __restrict__ perm)
{
    int cell = blockIdx.x * blockDim.x + threadIdx.x;  // N_CELLS = 8192*256
    unsigned int w = packed[cell];
    unsigned int cc = w >> 24;
    if (cc < 2u) return;
    unsigned int s = w & 0xFFFFFFu;
    unsigned int e = (cc == 255u) ? (packed[cell + 1] & 0xFFFFFFu) : s + cc;
#pragma unroll
    for (int c = 0; c < 8; ++c) {
        float a[10];
#pragma unroll
        for (int j = 0; j < 10; ++j) a[j] = 0.0f;
        for (unsigned int r = s; r < e; ++r) acc_row(perm, (long)r, c, a);
        unsigned int* d = perm + (long)s * 48 + c * 6;
        unsigned int w0 = f2bf(a[0]) | (f2bf(a[1]) << 16);
        unsigned int w1 = f2bf(a[2]) | (f2bf(a[3]) << 16);
        unsigned int w2 = f2bf(a[4]) | (f2bf(a[5]) << 16);
        unsigned int w3 = f2bf(a[6]) | (f2bf(a[7]) << 16);
        unsigned int w4 = f2bf(a[8]) | (f2bf(a[9]) << 16);
        *(uint2*)(d)     = make_uint2(w0, w1);
        *(uint2*)(d + 2) = make_uint2(w2, w3);
        d[4] = w4;
    }
}

// --- K7: vertex gather: per neighbor cell exactly one packed load + one row ---
__global__ void __launch_bounds__(256) gather_perm(const unsigned int* __restrict__ packed,
                                                   const unsigned int* __restrict__ perm,
                                                   float* __restrict__ vout)
{
    int vid = blockIdx.x * blockDim.x + threadIdx.x;
    if (vid >= N_VERTS) return;
    int z = vid % RES_V;
    int tmp = vid / RES_V;
    int y = tmp % RES_V;
    int x = tmp / RES_V;

    float sums[10];
#pragma unroll
    for (int j = 0; j < 10; ++j) sums[j] = 0.0f;
    int cnt = 0;

#pragma unroll
    for (int dx = 0; dx < 2; ++dx) {
        int cx = x - dx;
        if ((unsigned)cx >= RES) continue;
#pragma unroll
        for (int dy = 0; dy < 2; ++dy) {
            int cy = y - dy;
            if ((unsigned)cy >= RES) continue;
#pragma unroll
            for (int dz = 0; dz < 2; ++dz) {
                int cz = z - dz;
                if ((unsigned)cz >= RES) continue;
                int cid = (cx * RES + cy) * RES + cz;
                unsigned int w = packed[cid];
                unsigned int cc = w >> 24;
                if (cc == 0u) continue;
                unsigned int s = w & 0xFFFFFFu;
                if (cc == 255u) cnt += (int)((packed[cid + 1] & 0xFFFFFFu) - s);
                else cnt += (int)cc;
                acc_row(perm, (long)s, dx + 2 * dy + 4 * dz, sums);
            }
        }
    }

    float fc = (float)cnt;
    float inv = 1.0f / fmaxf(fc, 1.0f);
    float o[10];
    o[0] = (float)x * INV_RES - 0.5f + DEFORM_SCALE * tanhf(sums[1] * inv);
    o[1] = (float)y * INV_RES - 0.5f + DEFORM_SCALE * tanhf(sums[2] * inv);
    o[2] = (float)z * INV_RES - 0.5f + DEFORM_SCALE * tanhf(sums[3] * inv);
    o[3] = (sums[0] + fc * SDF_BIAS) * inv;
#pragma unroll
    for (int j = 0; j < 6; ++j) o[4 + j] = sums[4 + j] * inv;

    float* p = vout + (long)vid * 10;
#pragma unroll
    for (int j = 0; j < 5; ++j)
        *(float2*)(p + 2 * j) = make_float2(o[2 * j], o[2 * j + 1]);
}

// --- K8: weights grid, one thread per CELL; cc==1 fast path; LDS transpose ---
__global__ void __launch_bounds__(256) weights_fill2(const float* __restrict__ feats,
                                                     const unsigned int* __restrict__ packed,
                                                     const unsigned int* __restrict__ list,
                                                     float* __restrict__ outw)
{
    __shared__ float vals[256 * 21];
    int t = threadIdx.x;
    int cell0 = blockIdx.x * 256;
    int cell = cell0 + t;                 // N_CELLS = 8192*256 exactly

    unsigned int w = packed[cell];
    unsigned int cc = w >> 24;
    if (cc > 0u) {
        unsigned int s = w & 0xFFFFFFu;
        unsigned int li;
        if (cc == 1u) {
            li = list[s];
        } else {
            unsigned int e = (cc == 255u) ? (packed[cell + 1] & 0xFFFFFFu) : s + cc;
            li = 0u;
            for (unsigned int i = s; i < e; ++i) li = max(li, list[i]);
        }
        const float* f = feats + (long)li * 101 + 32;
#pragma unroll
        for (int j = 0; j < 21; ++j) vals[t * 21 + j] = f[j];
    } else {
#pragma unroll
        for (int j = 0; j < 21; ++j) vals[t * 21 + j] = 0.0f;
    }
    __syncthreads();

    float* dst = outw + (long)cell0 * 21;
#pragma unroll
    for (int k = 0; k < 21; ++k) dst[t + 256 * k] = vals[t + 256 * k];
}

extern "C" void kernel_launch(void* const* d_in, const int* in_sizes, int n_in,
                              void* d_out, int out_size, void* d_ws, size_t ws_size,
                              hipStream_t stream) {
    const int* coords = (const int*)d_in[0];
    const float* feats = (const float*)d_in[1];
    float* out = (float*)d_out;
    float* vout = out;                          // [N_VERTS*10]
    float* outw = out + VOUT_WORDS;             // [N_CELLS*21]

    // d_ws (~10 MB): packed[N_CELLS+1], list[N_VOX], blocksums[512]
    unsigned int* packed = (unsigned int*)d_ws;
    unsigned int* list = packed + (N_CELLS + 1);
    unsigned int* blocksums = list + N_VOX;

    // In the outw region (all dead before weights_fill2 overwrites it):
    //   perm:       head, 400k*48 uints (76.8 MB)
    //   cnt_cursor: tail, N_CELLS words (19.2M..76.8M < 41.9M start? checked:
    //     perm ends at word 19,200,000; cnt_cursor starts at 41,943,022) OK
    unsigned int* perm = (unsigned int*)outw;
    unsigned int* cnt_cursor = (unsigned int*)(outw + (OUTW_WORDS - N_CELLS - 16));

    hipMemsetAsync(cnt_cursor, 0, sizeof(unsigned int) * (size_t)N_CELLS, stream);
    count_kernel<<<(N_VOX + 255) / 256, 256, 0, stream>>>(coords, cnt_cursor);
    scan1_kernel<<<SCAN_BLOCKS, 256, 0, stream>>>(cnt_cursor, packed, blocksums);
    fixup2_kernel<<<N_CELLS / 256, 256, 0, stream>>>(packed, cnt_cursor, blocksums);
    fill_kernel<<<(N_VOX + 255) / 256, 256, 0, stream>>>(coords, cnt_cursor, list);
    permute_kernel<<<(N_VOX * 8 + 255) / 256, 256, 0, stream>>>(feats, list, perm);
    aggregate_kernel<<<N_CELLS / 256, 256, 0, stream>>>(packed, perm);
    gather_perm<<<GATHER_BLOCKS, 256, 0, stream>>>(packed, perm, vout);
    weights_fill2<<<N_CELLS / 256, 256, 0, stream>>>(feats, packed, list, outw);
}

// Round 12
// 254.411 us; speedup vs baseline: 1.0882x; 1.0882x over previous
//
#include <hip/hip_runtime.h>

#define RES 128
#define RES_V 129
#define N_VOX 400000

constexpr int N_VERTS = RES_V * RES_V * RES_V;   // 2146689
constexpr int N_CELLS = RES * RES * RES;         // 2097152
constexpr long VOUT_WORDS = (long)N_VERTS * 10;  // 21466890
constexpr long OUTW_WORDS = (long)N_CELLS * 21;  // 44040192
constexpr int SCAN_BLOCKS = 512;                 // N_CELLS / 4096
constexpr int GATHER_BLOCKS = (N_VERTS + 255) / 256;  // 8386
constexpr float SDF_BIAS = -1.0f / 128.0f;
constexpr float DEFORM_SCALE = (float)((1.0 - 1e-8) / 256.0);
constexpr float INV_RES = 1.0f / 128.0f;

// bf16 pack/unpack (round-to-nearest-even)
static __device__ __forceinline__ unsigned int f2bf(float x) {
    unsigned int u = __float_as_uint(x);
    unsigned int r = ((u >> 16) & 1u) + 0x7FFFu;
    return (u + r) >> 16;
}
static __device__ __forceinline__ float bf_lo(unsigned int w) {
    return __uint_as_float(w << 16);
}
static __device__ __forceinline__ float bf_hi(unsigned int w) {
    return __uint_as_float(w & 0xFFFF0000u);
}

// --- K0: zero the cell histogram ---
__global__ void __launch_bounds__(256) init_counts(unsigned int* __restrict__ counts)
{
    int t = blockIdx.x * blockDim.x + threadIdx.x;
    if (t < N_CELLS) counts[t] = 0u;
}

// --- K1: per-voxel cell histogram ---
__global__ void __launch_bounds__(256) count_kernel(const int* __restrict__ coords,
                                                    unsigned int* __restrict__ counts)
{
    int n = blockIdx.x * blockDim.x + threadIdx.x;
    if (n >= N_VOX) return;
    int cx = coords[n * 3 + 0];
    int cy = coords[n * 3 + 1];
    int cz = coords[n * 3 + 2];
    int cid = (cx * RES + cy) * RES + cz;
    atomicAdd(counts + cid, 1u);
}

// --- K2: block-local exclusive scan (4096 elems / block) -> packed(local) ---
__global__ void __launch_bounds__(256) scan1_kernel(const unsigned int* __restrict__ counts,
                                                    unsigned int* __restrict__ packed,
                                                    unsigned int* __restrict__ blocksums)
{
    __shared__ unsigned int part[256];
    int b = blockIdx.x, t = threadIdx.x;
    long base = (long)b * 4096 + (long)t * 16;
    unsigned int v[16], s = 0;
#pragma unroll
    for (int i = 0; i < 16; ++i) { v[i] = counts[base + i]; s += v[i]; }
    part[t] = s;
    __syncthreads();
    for (int off = 1; off < 256; off <<= 1) {
        unsigned int x = (t >= off) ? part[t - off] : 0u;
        __syncthreads();
        part[t] += x;
        __syncthreads();
    }
    unsigned int excl = (t == 0) ? 0u : part[t - 1];
    if (t == 255) blocksums[b] = part[255];
    unsigned int run = excl;
#pragma unroll
    for (int i = 0; i < 16; ++i) { packed[base + i] = run; run += v[i]; }
}

// --- K3: globalize + pack count into high byte; init cursors; sentinel ---
__global__ void __launch_bounds__(256) fixup2_kernel(unsigned int* __restrict__ packed,
                                                     unsigned int* __restrict__ cnt_cursor,
                                                     const unsigned int* __restrict__ blocksums)
{
    __shared__ unsigned int red[256];
    int t = threadIdx.x;
    int cell0 = blockIdx.x * 256;
    int R = cell0 >> 12;
    unsigned int part = 0;
    for (int j = t; j < R; j += 256) part += blocksums[j];
    red[t] = part;
    __syncthreads();
    for (int off = 128; off > 0; off >>= 1) {
        if (t < off) red[t] += red[t + off];
        __syncthreads();
    }
    unsigned int P = red[0];
    int cell = cell0 + t;
    unsigned int g = packed[cell] + P;
    unsigned int cnt = cnt_cursor[cell];
    packed[cell] = g | (min(cnt, 255u) << 24);
    cnt_cursor[cell] = g;
    if (cell == 0) packed[N_CELLS] = (unsigned int)N_VOX;
}

// --- K4: fill CSR list ---
__global__ void __launch_bounds__(256) fill_kernel(const int* __restrict__ coords,
                                                   unsigned int* __restrict__ cursors,
                                                   unsigned int* __restrict__ list)
{
    int n = blockIdx.x * blockDim.x + threadIdx.x;
    if (n >= N_VOX) return;
    int cx = coords[n * 3 + 0];
    int cy = coords[n * 3 + 1];
    int cz = coords[n * 3 + 2];
    int cid = (cx * RES + cy) * RES + cz;
    unsigned int slot = atomicAdd(cursors + cid, 1u);
    list[slot] = (unsigned int)n;
}

// --- K5: permute feats into cell-sorted, corner-SoA bf16 rows ---
// 8 threads per slot; thread c packs its corner's 10 floats into 5 uints
// (2 bf16 each) at perm[slot*40 + c*5 .. +5).
__global__ void __launch_bounds__(256) permute_kernel(const float* __restrict__ feats,
                                                      const unsigned int* __restrict__ list,
                                                      unsigned int* __restrict__ perm)
{
    int g = blockIdx.x * blockDim.x + threadIdx.x;
    int slot = g >> 3;
    int c = g & 7;
    if (slot >= N_VOX) return;
    long src = (long)list[slot] * 101;
    float v[10];
    v[0] = __builtin_nontemporal_load(feats + src + c);
#pragma unroll
    for (int k = 0; k < 3; ++k) v[1 + k] = __builtin_nontemporal_load(feats + src + 8 + 3 * c + k);
#pragma unroll
    for (int k = 0; k < 6; ++k) v[4 + k] = __builtin_nontemporal_load(feats + src + 53 + 6 * c + k);
    unsigned int* d = perm + (long)slot * 40 + c * 5;
#pragma unroll
    for (int q = 0; q < 5; ++q)
        d[q] = f2bf(v[2 * q]) | (f2bf(v[2 * q + 1]) << 16);
}

// --- K6: vertex gather from permuted bf16 rows; packed starts ---
__global__ void __launch_bounds__(256) gather_perm(const unsigned int* __restrict__ packed,
                                                   const unsigned int* __restrict__ perm,
                                                   float* __restrict__ vout)
{
    int vid = blockIdx.x * blockDim.x + threadIdx.x;
    if (vid >= N_VERTS) return;
    int z = vid % RES_V;
    int tmp = vid / RES_V;
    int y = tmp % RES_V;
    int x = tmp / RES_V;

    float sums[10];
#pragma unroll
    for (int j = 0; j < 10; ++j) sums[j] = 0.0f;
    int cnt = 0;

#pragma unroll
    for (int dx = 0; dx < 2; ++dx) {
        int cx = x - dx;
        if ((unsigned)cx >= RES) continue;
#pragma unroll
        for (int dy = 0; dy < 2; ++dy) {
            int cy = y - dy;
            if ((unsigned)cy >= RES) continue;
#pragma unroll
            for (int dz = 0; dz < 2; ++dz) {
                int cz = z - dz;
                if ((unsigned)cz >= RES) continue;
                int cid = (cx * RES + cy) * RES + cz;
                unsigned int w = packed[cid];
                unsigned int cc = w >> 24;
                if (cc == 0u) continue;
                unsigned int s = w & 0xFFFFFFu;
                unsigned int e = (cc == 255u) ? (packed[cid + 1] & 0xFFFFFFu)
                                              : s + cc;
                int c = dx + 2 * dy + 4 * dz;
                for (unsigned int ii = s; ii < e; ++ii) {
                    const unsigned int* b = perm + (long)ii * 40 + c * 5;
                    unsigned int w0 = b[0], w1 = b[1], w2 = b[2], w3 = b[3], w4 = b[4];
                    sums[0] += bf_lo(w0); sums[1] += bf_hi(w0);
                    sums[2] += bf_lo(w1); sums[3] += bf_hi(w1);
                    sums[4] += bf_lo(w2); sums[5] += bf_hi(w2);
                    sums[6] += bf_lo(w3); sums[7] += bf_hi(w3);
                    sums[8] += bf_lo(w4); sums[9] += bf_hi(w4);
                }
                cnt += (int)(e - s);
            }
        }
    }

    float fc = (float)cnt;
    float inv = 1.0f / fmaxf(fc, 1.0f);
    float o[10];
    o[0] = (float)x * INV_RES - 0.5f + DEFORM_SCALE * tanhf(sums[1] * inv);
    o[1] = (float)y * INV_RES - 0.5f + DEFORM_SCALE * tanhf(sums[2] * inv);
    o[2] = (float)z * INV_RES - 0.5f + DEFORM_SCALE * tanhf(sums[3] * inv);
    o[3] = (sums[0] + fc * SDF_BIAS) * inv;
#pragma unroll
    for (int j = 0; j < 6; ++j) o[4 + j] = sums[4 + j] * inv;

    float* p = vout + (long)vid * 10;
#pragma unroll
    for (int j = 0; j < 10; ++j)
        __builtin_nontemporal_store(o[j], p + j);
}

// --- K7: weights grid, one thread per CELL; cc==1 fast path; LDS transpose ---
__global__ void __launch_bounds__(256) weights_fill2(const float* __restrict__ feats,
                                                     const unsigned int* __restrict__ packed,
                                                     const unsigned int* __restrict__ list,
                                                     float* __restrict__ outw)
{
    __shared__ float vals[256 * 21];
    int t = threadIdx.x;
    int cell0 = blockIdx.x * 256;
    int cell = cell0 + t;                 // N_CELLS = 8192*256 exactly

    unsigned int w = packed[cell];
    unsigned int cc = w >> 24;
    if (cc > 0u) {
        unsigned int s = w & 0xFFFFFFu;
        unsigned int li;
        if (cc == 1u) {
            li = list[s];                  // fast path: single contributor
        } else {
            unsigned int e = (cc == 255u) ? (packed[cell + 1] & 0xFFFFFFu) : s + cc;
            li = 0u;
            for (unsigned int i = s; i < e; ++i) li = max(li, list[i]);
        }
        const float* f = feats + (long)li * 101 + 32;
#pragma unroll
        for (int j = 0; j < 21; ++j) vals[t * 21 + j] = __builtin_nontemporal_load(f + j);
    } else {
#pragma unroll
        for (int j = 0; j < 21; ++j) vals[t * 21 + j] = 0.0f;
    }
    __syncthreads();

    float* dst = outw + (long)cell0 * 21;
#pragma unroll
    for (int k = 0; k < 21; ++k)
        __builtin_nontemporal_store(vals[t + 256 * k], dst + t + 256 * k);
}

extern "C" void kernel_launch(void* const* d_in, const int* in_sizes, int n_in,
                              void* d_out, int out_size, void* d_ws, size_t ws_size,
                              hipStream_t stream) {
    const int* coords = (const int*)d_in[0];
    const float* feats = (const float*)d_in[1];
    float* out = (float*)d_out;
    float* vout = out;                          // [N_VERTS*10]
    float* outw = out + VOUT_WORDS;             // [N_CELLS*21]

    // d_ws (~10 MB): packed[N_CELLS+1], list[N_VOX], blocksums[512]
    unsigned int* packed = (unsigned int*)d_ws;
    unsigned int* list = packed + (N_CELLS + 1);
    unsigned int* blocksums = list + N_VOX;

    // In the outw region (all dead before weights_fill2 overwrites it):
    //   perm:       head, 400k*40 uints (64 MB)
    //   cnt_cursor: tail, N_CELLS words — disjoint from perm
    unsigned int* perm = (unsigned int*)outw;
    unsigned int* cnt_cursor = (unsigned int*)(outw + (OUTW_WORDS - N_CELLS - 16));

    init_counts<<<(N_CELLS + 255) / 256, 256, 0, stream>>>(cnt_cursor);
    count_kernel<<<(N_VOX + 255) / 256, 256, 0, stream>>>(coords, cnt_cursor);
    scan1_kernel<<<SCAN_BLOCKS, 256, 0, stream>>>(cnt_cursor, packed, blocksums);
    fixup2_kernel<<<N_CELLS / 256, 256, 0, stream>>>(packed, cnt_cursor, blocksums);
    fill_kernel<<<(N_VOX + 255) / 256, 256, 0, stream>>>(coords, cnt_cursor, list);
    permute_kernel<<<(N_VOX * 8 + 255) / 256, 256, 0, stream>>>(feats, list, perm);
    gather_perm<<<GATHER_BLOCKS, 256, 0, stream>>>(packed, perm, vout);
    weights_fill2<<<N_CELLS / 256, 256, 0, stream>>>(feats, packed, list, outw);
}

// Round 13
// 232.167 us; speedup vs baseline: 1.1925x; 1.0958x over previous
//
#include <hip/hip_runtime.h>

#define RES 128
#define RES_V 129
#define N_VOX 400000

constexpr int N_VERTS = RES_V * RES_V * RES_V;   // 2146689
constexpr int N_CELLS = RES * RES * RES;         // 2097152
constexpr long VOUT_WORDS = (long)N_VERTS * 10;  // 21466890
constexpr long OUTW_WORDS = (long)N_CELLS * 21;  // 44040192
constexpr int SCAN_BLOCKS = 512;                 // N_CELLS / 4096
constexpr int GATHER_BLOCKS = (N_VERTS + 255) / 256;  // 8386
constexpr float SDF_BIAS = -1.0f / 128.0f;
constexpr float DEFORM_SCALE = (float)((1.0 - 1e-8) / 256.0);
constexpr float INV_RES = 1.0f / 128.0f;

// bf16 pack/unpack (round-to-nearest-even)
static __device__ __forceinline__ unsigned int f2bf(float x) {
    unsigned int u = __float_as_uint(x);
    unsigned int r = ((u >> 16) & 1u) + 0x7FFFu;
    return (u + r) >> 16;
}
static __device__ __forceinline__ float bf_lo(unsigned int w) {
    return __uint_as_float(w << 16);
}
static __device__ __forceinline__ float bf_hi(unsigned int w) {
    return __uint_as_float(w & 0xFFFF0000u);
}

// --- K0: zero the cell histogram ---
__global__ void __launch_bounds__(256) init_counts(unsigned int* __restrict__ counts)
{
    int t = blockIdx.x * blockDim.x + threadIdx.x;
    if (t < N_CELLS) counts[t] = 0u;
}

// --- K1: per-voxel cell histogram ---
__global__ void __launch_bounds__(256) count_kernel(const int* __restrict__ coords,
                                                    unsigned int* __restrict__ counts)
{
    int n = blockIdx.x * blockDim.x + threadIdx.x;
    if (n >= N_VOX) return;
    int cx = coords[n * 3 + 0];
    int cy = coords[n * 3 + 1];
    int cz = coords[n * 3 + 2];
    int cid = (cx * RES + cy) * RES + cz;
    atomicAdd(counts + cid, 1u);
}

// --- K2: block-local exclusive scan (4096 elems / block) -> packed(local) ---
__global__ void __launch_bounds__(256) scan1_kernel(const unsigned int* __restrict__ counts,
                                                    unsigned int* __restrict__ packed,
                                                    unsigned int* __restrict__ blocksums)
{
    __shared__ unsigned int part[256];
    int b = blockIdx.x, t = threadIdx.x;
    long base = (long)b * 4096 + (long)t * 16;
    unsigned int v[16], s = 0;
#pragma unroll
    for (int i = 0; i < 16; ++i) { v[i] = counts[base + i]; s += v[i]; }
    part[t] = s;
    __syncthreads();
    for (int off = 1; off < 256; off <<= 1) {
        unsigned int x = (t >= off) ? part[t - off] : 0u;
        __syncthreads();
        part[t] += x;
        __syncthreads();
    }
    unsigned int excl = (t == 0) ? 0u : part[t - 1];
    if (t == 255) blocksums[b] = part[255];
    unsigned int run = excl;
#pragma unroll
    for (int i = 0; i < 16; ++i) { packed[base + i] = run; run += v[i]; }
}

// --- K3: globalize + pack count into high byte; init cursors; sentinel ---
__global__ void __launch_bounds__(256) fixup2_kernel(unsigned int* __restrict__ packed,
                                                     unsigned int* __restrict__ cnt_cursor,
                                                     const unsigned int* __restrict__ blocksums)
{
    __shared__ unsigned int red[256];
    int t = threadIdx.x;
    int cell0 = blockIdx.x * 256;
    int R = cell0 >> 12;
    unsigned int part = 0;
    for (int j = t; j < R; j += 256) part += blocksums[j];
    red[t] = part;
    __syncthreads();
    for (int off = 128; off > 0; off >>= 1) {
        if (t < off) red[t] += red[t + off];
        __syncthreads();
    }
    unsigned int P = red[0];
    int cell = cell0 + t;
    unsigned int g = packed[cell] + P;
    unsigned int cnt = cnt_cursor[cell];
    packed[cell] = g | (min(cnt, 255u) << 24);
    cnt_cursor[cell] = g;
    if (cell == 0) packed[N_CELLS] = (unsigned int)N_VOX;
}

// --- K4: fill CSR list ---
__global__ void __launch_bounds__(256) fill_kernel(const int* __restrict__ coords,
                                                   unsigned int* __restrict__ cursors,
                                                   unsigned int* __restrict__ list)
{
    int n = blockIdx.x * blockDim.x + threadIdx.x;
    if (n >= N_VOX) return;
    int cx = coords[n * 3 + 0];
    int cy = coords[n * 3 + 1];
    int cz = coords[n * 3 + 2];
    int cid = (cx * RES + cy) * RES + cz;
    unsigned int slot = atomicAdd(cursors + cid, 1u);
    list[slot] = (unsigned int)n;
}

// --- K5: permute feats into cell-sorted, corner-SoA bf16 rows ---
// 8 threads per slot; thread c packs its corner's 10 floats into 5 uints
// (2 bf16 each) at perm[slot*40 + c*5 .. +5).
__global__ void __launch_bounds__(256) permute_kernel(const float* __restrict__ feats,
                                                      const unsigned int* __restrict__ list,
                                                      unsigned int* __restrict__ perm)
{
    int g = blockIdx.x * blockDim.x + threadIdx.x;
    int slot = g >> 3;
    int c = g & 7;
    if (slot >= N_VOX) return;
    long src = (long)list[slot] * 101;
    float v[10];
    v[0] = feats[src + c];
#pragma unroll
    for (int k = 0; k < 3; ++k) v[1 + k] = feats[src + 8 + 3 * c + k];
#pragma unroll
    for (int k = 0; k < 6; ++k) v[4 + k] = feats[src + 53 + 6 * c + k];
    unsigned int* d = perm + (long)slot * 40 + c * 5;
#pragma unroll
    for (int q = 0; q < 5; ++q)
        d[q] = f2bf(v[2 * q]) | (f2bf(v[2 * q + 1]) << 16);
}

// --- K6: vertex-linear gather from permuted bf16 rows (20B per visit) ---
__global__ void __launch_bounds__(256) gather_perm(const unsigned int* __restrict__ packed,
                                                   const unsigned int* __restrict__ perm,
                                                   float* __restrict__ vout)
{
    int vid = blockIdx.x * blockDim.x + threadIdx.x;
    if (vid >= N_VERTS) return;
    int z = vid % RES_V;
    int tmp = vid / RES_V;
    int y = tmp % RES_V;
    int x = tmp / RES_V;

    float sums[10];
#pragma unroll
    for (int j = 0; j < 10; ++j) sums[j] = 0.0f;
    int cnt = 0;

#pragma unroll
    for (int dx = 0; dx < 2; ++dx) {
        int cx = x - dx;
        if ((unsigned)cx >= RES) continue;
#pragma unroll
        for (int dy = 0; dy < 2; ++dy) {
            int cy = y - dy;
            if ((unsigned)cy >= RES) continue;
#pragma unroll
            for (int dz = 0; dz < 2; ++dz) {
                int cz = z - dz;
                if ((unsigned)cz >= RES) continue;
                int cid = (cx * RES + cy) * RES + cz;
                unsigned int w = packed[cid];
                unsigned int cc = w >> 24;
                if (cc == 0u) continue;
                unsigned int s = w & 0xFFFFFFu;
                unsigned int e = (cc == 255u) ? (packed[cid + 1] & 0xFFFFFFu)
                                              : s + cc;
                int c = dx + 2 * dy + 4 * dz;
                for (unsigned int i = s; i < e; ++i) {
                    const unsigned int* b = perm + (long)i * 40 + c * 5;
                    unsigned int w0 = b[0], w1 = b[1], w2 = b[2], w3 = b[3], w4 = b[4];
                    sums[0] += bf_lo(w0); sums[1] += bf_hi(w0);
                    sums[2] += bf_lo(w1); sums[3] += bf_hi(w1);
                    sums[4] += bf_lo(w2); sums[5] += bf_hi(w2);
                    sums[6] += bf_lo(w3); sums[7] += bf_hi(w3);
                    sums[8] += bf_lo(w4); sums[9] += bf_hi(w4);
                }
                cnt += (int)(e - s);
            }
        }
    }

    float fc = (float)cnt;
    float inv = 1.0f / fmaxf(fc, 1.0f);
    float o[10];
    o[0] = (float)x * INV_RES - 0.5f + DEFORM_SCALE * tanhf(sums[1] * inv);
    o[1] = (float)y * INV_RES - 0.5f + DEFORM_SCALE * tanhf(sums[2] * inv);
    o[2] = (float)z * INV_RES - 0.5f + DEFORM_SCALE * tanhf(sums[3] * inv);
    o[3] = (sums[0] + fc * SDF_BIAS) * inv;
#pragma unroll
    for (int j = 0; j < 6; ++j) o[4 + j] = sums[4 + j] * inv;

    float* p = vout + (long)vid * 10;
#pragma unroll
    for (int j = 0; j < 5; ++j)
        *(float2*)(p + 2 * j) = make_float2(o[2 * j], o[2 * j + 1]);
}

// --- K7: weights grid, one thread per CELL; cc==1 fast path; LDS transpose ---
__global__ void __launch_bounds__(256) weights_fill2(const float* __restrict__ feats,
                                                     const unsigned int* __restrict__ packed,
                                                     const unsigned int* __restrict__ list,
                                                     float* __restrict__ outw)
{
    __shared__ float vals[256 * 21];
    int t = threadIdx.x;
    int cell0 = blockIdx.x * 256;
    int cell = cell0 + t;                 // N_CELLS = 8192*256 exactly

    unsigned int w = packed[cell];
    unsigned int cc = w >> 24;
    if (cc > 0u) {
        unsigned int s = w & 0xFFFFFFu;
        unsigned int li;
        if (cc == 1u) {
            li = list[s];                  // fast path: 91% of occupied cells
        } else {
            unsigned int e = (cc == 255u) ? (packed[cell + 1] & 0xFFFFFFu) : s + cc;
            li = 0u;
            for (unsigned int i = s; i < e; ++i) li = max(li, list[i]);
        }
        const float* f = feats + (long)li * 101 + 32;
#pragma unroll
        for (int j = 0; j < 21; ++j) vals[t * 21 + j] = f[j];
    } else {
#pragma unroll
        for (int j = 0; j < 21; ++j) vals[t * 21 + j] = 0.0f;
    }
    __syncthreads();

    float* dst = outw + (long)cell0 * 21;
#pragma unroll
    for (int k = 0; k < 21; ++k) dst[t + 256 * k] = vals[t + 256 * k];
}

extern "C" void kernel_launch(void* const* d_in, const int* in_sizes, int n_in,
                              void* d_out, int out_size, void* d_ws, size_t ws_size,
                              hipStream_t stream) {
    const int* coords = (const int*)d_in[0];
    const float* feats = (const float*)d_in[1];
    float* out = (float*)d_out;
    float* vout = out;                          // [N_VERTS*10]
    float* outw = out + VOUT_WORDS;             // [N_CELLS*21]

    // d_ws (~10 MB): packed[N_CELLS+1], list[N_VOX], blocksums[512]
    unsigned int* packed = (unsigned int*)d_ws;
    unsigned int* list = packed + (N_CELLS + 1);
    unsigned int* blocksums = list + N_VOX;

    // In the outw region (all dead before weights_fill2 overwrites it):
    //   perm:       head, 400k*40 uints (64 MB)
    //   cnt_cursor: tail, N_CELLS words — disjoint from perm
    unsigned int* perm = (unsigned int*)outw;
    unsigned int* cnt_cursor = (unsigned int*)(outw + (OUTW_WORDS - N_CELLS - 16));

    init_counts<<<(N_CELLS + 255) / 256, 256, 0, stream>>>(cnt_cursor);
    count_kernel<<<(N_VOX + 255) / 256, 256, 0, stream>>>(coords, cnt_cursor);
    scan1_kernel<<<SCAN_BLOCKS, 256, 0, stream>>>(cnt_cursor, packed, blocksums);
    fixup2_kernel<<<N_CELLS / 256, 256, 0, stream>>>(packed, cnt_cursor, blocksums);
    fill_kernel<<<(N_VOX + 255) / 256, 256, 0, stream>>>(coords, cnt_cursor, list);
    permute_kernel<<<(N_VOX * 8 + 255) / 256, 256, 0, stream>>>(feats, list, perm);
    gather_perm<<<GATHER_BLOCKS, 256, 0, stream>>>(packed, perm, vout);
    weights_fill2<<<N_CELLS / 256, 256, 0, stream>>>(feats, packed, list, outw);
}

// Round 14
// 221.382 us; speedup vs baseline: 1.2506x; 1.0487x over previous
//
#include <hip/hip_runtime.h>

#define RES 128
#define RES_V 129
#define N_VOX 400000

constexpr int N_VERTS = RES_V * RES_V * RES_V;   // 2146689
constexpr int N_CELLS = RES * RES * RES;         // 2097152
constexpr long VOUT_WORDS = (long)N_VERTS * 10;  // 21466890
constexpr long OUTW_WORDS = (long)N_CELLS * 21;  // 44040192
constexpr int SCAN_BLOCKS = 512;                 // N_CELLS / 4096
constexpr float SDF_BIAS = -1.0f / 128.0f;
constexpr float DEFORM_SCALE = (float)((1.0 - 1e-8) / 256.0);
constexpr float INV_RES = 1.0f / 128.0f;

// bf16 pack/unpack (round-to-nearest-even)
static __device__ __forceinline__ unsigned int f2bf(float x) {
    unsigned int u = __float_as_uint(x);
    unsigned int r = ((u >> 16) & 1u) + 0x7FFFu;
    return (u + r) >> 16;
}
static __device__ __forceinline__ float bf_lo(unsigned int w) {
    return __uint_as_float(w << 16);
}
static __device__ __forceinline__ float bf_hi(unsigned int w) {
    return __uint_as_float(w & 0xFFFF0000u);
}

// --- K0: zero the cell histogram ---
__global__ void __launch_bounds__(256) init_counts(unsigned int* __restrict__ counts)
{
    int t = blockIdx.x * blockDim.x + threadIdx.x;
    if (t < N_CELLS) counts[t] = 0u;
}

// --- K1: per-voxel cell histogram ---
__global__ void __launch_bounds__(256) count_kernel(const int* __restrict__ coords,
                                                    unsigned int* __restrict__ counts)
{
    int n = blockIdx.x * blockDim.x + threadIdx.x;
    if (n >= N_VOX) return;
    int cx = coords[n * 3 + 0];
    int cy = coords[n * 3 + 1];
    int cz = coords[n * 3 + 2];
    int cid = (cx * RES + cy) * RES + cz;
    atomicAdd(counts + cid, 1u);
}

// --- K2: block-local exclusive scan (4096 elems / block) -> starts(local) ---
__global__ void __launch_bounds__(256) scan1_kernel(const unsigned int* __restrict__ counts,
                                                    unsigned int* __restrict__ starts,
                                                    unsigned int* __restrict__ blocksums)
{
    __shared__ unsigned int part[256];
    int b = blockIdx.x, t = threadIdx.x;
    long base = (long)b * 4096 + (long)t * 16;
    unsigned int v[16], s = 0;
#pragma unroll
    for (int i = 0; i < 16; ++i) { v[i] = counts[base + i]; s += v[i]; }
    part[t] = s;
    __syncthreads();
    for (int off = 1; off < 256; off <<= 1) {
        unsigned int x = (t >= off) ? part[t - off] : 0u;
        __syncthreads();
        part[t] += x;
        __syncthreads();
    }
    unsigned int excl = (t == 0) ? 0u : part[t - 1];
    if (t == 255) blocksums[b] = part[255];
    unsigned int run = excl;
#pragma unroll
    for (int i = 0; i < 16; ++i) { starts[base + i] = run; run += v[i]; }
}

// --- K3: exclusive scan of the 512 block sums (single block) ---
__global__ void __launch_bounds__(512) scan2_kernel(unsigned int* __restrict__ blocksums)
{
    __shared__ unsigned int sh[SCAN_BLOCKS];
    int t = threadIdx.x;
    sh[t] = blocksums[t];
    __syncthreads();
    for (int off = 1; off < SCAN_BLOCKS; off <<= 1) {
        unsigned int x = (t >= off) ? sh[t - off] : 0u;
        __syncthreads();
        sh[t] += x;
        __syncthreads();
    }
    blocksums[t] = (t == 0) ? 0u : sh[t - 1];
}

// --- K4: globalize starts, copy to fill cursors, write sentinel ---
__global__ void __launch_bounds__(256) fixup_kernel(unsigned int* __restrict__ starts,
                                                    unsigned int* __restrict__ cursors,
                                                    const unsigned int* __restrict__ blocksums)
{
    int t = blockIdx.x * blockDim.x + threadIdx.x;
    if (t >= N_CELLS) return;
    unsigned int g = starts[t] + blocksums[t >> 12];
    starts[t] = g;
    cursors[t] = g;
    if (t == 0) starts[N_CELLS] = (unsigned int)N_VOX;
}

// --- K5: fill CSR list ---
__global__ void __launch_bounds__(256) fill_kernel(const int* __restrict__ coords,
                                                   unsigned int* __restrict__ cursors,
                                                   unsigned int* __restrict__ list)
{
    int n = blockIdx.x * blockDim.x + threadIdx.x;
    if (n >= N_VOX) return;
    int cx = coords[n * 3 + 0];
    int cy = coords[n * 3 + 1];
    int cz = coords[n * 3 + 2];
    int cid = (cx * RES + cy) * RES + cz;
    unsigned int slot = atomicAdd(cursors + cid, 1u);
    list[slot] = (unsigned int)n;
}

// --- K6: permute feats into cell-sorted, corner-SoA bf16 rows ---
// 8 threads per slot; thread c packs its corner's 10 floats into 5 uints
// (2 bf16 each) at perm[slot*40 + c*5 .. +5).
__global__ void __launch_bounds__(256) permute_kernel(const float* __restrict__ feats,
                                                      const unsigned int* __restrict__ list,
                                                      unsigned int* __restrict__ perm)
{
    int g = blockIdx.x * blockDim.x + threadIdx.x;
    int slot = g >> 3;
    int c = g & 7;
    if (slot >= N_VOX) return;
    long src = (long)list[slot] * 101;
    float v[10];
    v[0] = feats[src + c];
#pragma unroll
    for (int k = 0; k < 3; ++k) v[1 + k] = feats[src + 8 + 3 * c + k];
#pragma unroll
    for (int k = 0; k < 6; ++k) v[4 + k] = feats[src + 53 + 6 * c + k];
    unsigned int* d = perm + (long)slot * 40 + c * 5;
#pragma unroll
    for (int q = 0; q < 5; ++q)
        d[q] = f2bf(v[2 * q]) | (f2bf(v[2 * q + 1]) << 16);
}

// --- K7: vertex-linear gather from permuted bf16 rows (20B per visit) ---
__global__ void __launch_bounds__(256) gather_perm(const unsigned int* __restrict__ starts,
                                                   const unsigned int* __restrict__ perm,
                                                   float* __restrict__ vout)
{
    int vid = blockIdx.x * blockDim.x + threadIdx.x;
    if (vid >= N_VERTS) return;
    int z = vid % RES_V;
    int tmp = vid / RES_V;
    int y = tmp % RES_V;
    int x = tmp / RES_V;

    float sums[10];
#pragma unroll
    for (int j = 0; j < 10; ++j) sums[j] = 0.0f;
    int cnt = 0;

#pragma unroll
    for (int dx = 0; dx < 2; ++dx) {
        int cx = x - dx;
        if ((unsigned)cx >= RES) continue;
#pragma unroll
        for (int dy = 0; dy < 2; ++dy) {
            int cy = y - dy;
            if ((unsigned)cy >= RES) continue;
#pragma unroll
            for (int dz = 0; dz < 2; ++dz) {
                int cz = z - dz;
                if ((unsigned)cz >= RES) continue;
                int cid = (cx * RES + cy) * RES + cz;
                unsigned int s = starts[cid];
                unsigned int e = starts[cid + 1];
                if (s == e) continue;
                int c = dx + 2 * dy + 4 * dz;
                for (unsigned int i = s; i < e; ++i) {
                    const unsigned int* b = perm + (long)i * 40 + c * 5;
                    unsigned int w0 = b[0], w1 = b[1], w2 = b[2], w3 = b[3], w4 = b[4];
                    sums[0] += bf_lo(w0); sums[1] += bf_hi(w0);
                    sums[2] += bf_lo(w1); sums[3] += bf_hi(w1);
                    sums[4] += bf_lo(w2); sums[5] += bf_hi(w2);
                    sums[6] += bf_lo(w3); sums[7] += bf_hi(w3);
                    sums[8] += bf_lo(w4); sums[9] += bf_hi(w4);
                }
                cnt += (int)(e - s);
            }
        }
    }

    float fc = (float)cnt;
    float inv = 1.0f / fmaxf(fc, 1.0f);
    float o[10];
    o[0] = (float)x * INV_RES - 0.5f + DEFORM_SCALE * tanhf(sums[1] * inv);
    o[1] = (float)y * INV_RES - 0.5f + DEFORM_SCALE * tanhf(sums[2] * inv);
    o[2] = (float)z * INV_RES - 0.5f + DEFORM_SCALE * tanhf(sums[3] * inv);
    o[3] = (sums[0] + fc * SDF_BIAS) * inv;
#pragma unroll
    for (int j = 0; j < 6; ++j) o[4 + j] = sums[4 + j] * inv;

    float* p = vout + (long)vid * 10;
#pragma unroll
    for (int j = 0; j < 5; ++j)
        *(float2*)(p + 2 * j) = make_float2(o[2 * j], o[2 * j + 1]);
}

// --- K8: weights grid, one thread per CELL; LDS transpose for coalesced
// stores. vals[t*21+j]: stride 21 coprime with 32 banks -> conflict-free. ---
__global__ void __launch_bounds__(256) weights_fill2(const float* __restrict__ feats,
                                                     const unsigned int* __restrict__ starts,
                                                     const unsigned int* __restrict__ list,
                                                     float* __restrict__ outw)
{
    __shared__ float vals[256 * 21];
    int t = threadIdx.x;
    int cell0 = blockIdx.x * 256;
    int cell = cell0 + t;                 // N_CELLS = 8192*256 exactly

    unsigned int s = starts[cell];
    unsigned int e = starts[cell + 1];
    if (e > s) {
        unsigned int li = 0u;
        for (unsigned int i = s; i < e; ++i) li = max(li, list[i]);
        const float* f = feats + (long)li * 101 + 32;
#pragma unroll
        for (int j = 0; j < 21; ++j) vals[t * 21 + j] = f[j];
    } else {
#pragma unroll
        for (int j = 0; j < 21; ++j) vals[t * 21 + j] = 0.0f;
    }
    __syncthreads();

    float* dst = outw + (long)cell0 * 21;
#pragma unroll
    for (int k = 0; k < 21; ++k) dst[t + 256 * k] = vals[t + 256 * k];
}

extern "C" void kernel_launch(void* const* d_in, const int* in_sizes, int n_in,
                              void* d_out, int out_size, void* d_ws, size_t ws_size,
                              hipStream_t stream) {
    const int* coords = (const int*)d_in[0];
    const float* feats = (const float*)d_in[1];
    float* out = (float*)d_out;
    float* vout = out;                          // [N_VERTS*10]
    float* outw = out + VOUT_WORDS;             // [N_CELLS*21]

    // d_ws (~10 MB): starts[N_CELLS+1], list[N_VOX], blocksums[512]
    unsigned int* starts = (unsigned int*)d_ws;
    unsigned int* list = starts + (N_CELLS + 1);
    unsigned int* blocksums = list + N_VOX;

    // In the outw region (all dead before weights_fill2 overwrites it):
    //   perm:   head, 400k*40 uints = 16,000,000 words (64 MB)
    //   counts: tail, N_CELLS words — disjoint from perm
    unsigned int* perm = (unsigned int*)outw;
    unsigned int* counts = (unsigned int*)(outw + (OUTW_WORDS - N_CELLS - 16));

    init_counts<<<(N_CELLS + 255) / 256, 256, 0, stream>>>(counts);
    count_kernel<<<(N_VOX + 255) / 256, 256, 0, stream>>>(coords, counts);
    scan1_kernel<<<SCAN_BLOCKS, 256, 0, stream>>>(counts, starts, blocksums);
    scan2_kernel<<<1, SCAN_BLOCKS, 0, stream>>>(blocksums);
    fixup_kernel<<<(N_CELLS + 255) / 256, 256, 0, stream>>>(starts, counts, blocksums);
    fill_kernel<<<(N_VOX + 255) / 256, 256, 0, stream>>>(coords, counts, list);
    permute_kernel<<<(N_VOX * 8 + 255) / 256, 256, 0, stream>>>(feats, list, perm);
    gather_perm<<<(N_VERTS + 255) / 256, 256, 0, stream>>>(starts, perm, vout);
    weights_fill2<<<N_CELLS / 256, 256, 0, stream>>>(feats, starts, list, outw);
}